// Round 3
// baseline (3748.031 us; speedup 1.0000x reference)
//
#include <hip/hip_runtime.h>

// ESN leaky reservoir: res_{t+1} = 0.5*res_t + 0.5*tanh(x_t@i2h + res_t@h2h)
// Round 7: defeat the register allocator.
//  R6 post-mortem: VGPR_Count=64 proved neither A[8][2] (64 VGPR) nor bfr[8][2]
//  (64 VGPR) stayed resident -> loads re-serialized into the MFMA loop.
//  Fixes:
//   - B fragments live in LDS (128 KiB), pre-gathered in FRAGMENT-MAJOR order
//     ([wave][frag][lane][16B]) so every ds_read_b128 is linear (lane*16) and
//     conflict-free. No swizzle needed. B leaves the register budget AND the
//     global-load path.
//   - A loads: all 16 issued, then asm s_waitcnt vmcnt(0) w/ memory clobber.
//     Atomic loads can't be rematerialized or sunk past the clobber -> all 16
//     results (64 VGPR) are forced live -> ONE L3 latency for the tile.
//   - Partial reduce via a single pre-zeroed ds_add_f32 buffer pl[32][36]
//     (4.6 KiB): each thread reads its 2 summed slots after the barrier and
//     re-zeroes them for the next step. LDS total ~133 KiB (1 WG/CU; 128 WGs
//     on 256 CUs so co-residency unaffected).
//  Grid/flags/double-buffer proof unchanged from R6 (128 WGs = 2 row-halves x
//  64 col-groups; flag[rh*64+g] = last step published; post-GEMM barrier =>
//  WG observed all 64 row-half flags >= t => safe to overwrite parity (t+1)&1).

typedef _Float16 f16x8 __attribute__((ext_vector_type(8)));
typedef float f32x4 __attribute__((ext_vector_type(4)));
typedef float f32x2 __attribute__((ext_vector_type(2)));

#define NB 64      // batch
#define RDIM 2048  // reservoir
#define TT 256     // timesteps
#define IDIM 128   // input dim
#define NWG 128    // 2 row-halves x 64 col-groups
#define NTHR 512   // threads per WG (8 waves)

// ---------------- setup kernels ----------------

__global__ __launch_bounds__(256) void transpose_f32_to_f16(
    const float* __restrict__ in, _Float16* __restrict__ out, int rows, int cols) {
  __shared__ float tile[64][65];
  const int tx = threadIdx.x & 63;
  const int ty = threadIdx.x >> 6;
  const int rbase = blockIdx.y * 64;
  const int cbase = blockIdx.x * 64;
  for (int rr = ty; rr < 64; rr += 4)
    tile[rr][tx] = in[(size_t)(rbase + rr) * cols + cbase + tx];
  __syncthreads();
  for (int rr = ty; rr < 64; rr += 4)
    out[(size_t)(cbase + rr) * rows + rbase + tx] = (_Float16)tile[tx][rr];
}

__global__ __launch_bounds__(256) void convert_f32_f16(
    const float* __restrict__ in, _Float16* __restrict__ out, int n) {
  int i = blockIdx.x * 256 + threadIdx.x;
  int stride = gridDim.x * 256;
  for (; i < n; i += stride) out[i] = (_Float16)in[i];
}

__global__ __launch_bounds__(256) void init_zero(
    unsigned* __restrict__ res_words, unsigned* __restrict__ ctr_words) {
  int i = blockIdx.x * 256 + threadIdx.x;
  if (i < NB * RDIM / 2) res_words[i] = 0;  // res parity-0 buffer (fp16) = 0
  if (i < 4096) ctr_words[i] = 0;           // flags + readout ctr
}

// ---------------- coherent access helpers (sc0/sc1, no fences) ----------------

__device__ __forceinline__ f16x8 load_res16(const _Float16* p) {
  union { unsigned long long u[2]; f16x8 v; } r;
  const unsigned long long* q = (const unsigned long long*)p;
  r.u[0] = __hip_atomic_load(q, __ATOMIC_RELAXED, __HIP_MEMORY_SCOPE_SYSTEM);
  r.u[1] = __hip_atomic_load(q + 1, __ATOMIC_RELAXED, __HIP_MEMORY_SCOPE_SYSTEM);
  return r.v;
}

// flag[i] lives at ctrs[16*i] (64B spacing). Value = last published step index.
__device__ __forceinline__ void waitflag(const unsigned* p, unsigned tgt) {
  if (__hip_atomic_load(p, __ATOMIC_RELAXED, __HIP_MEMORY_SCOPE_SYSTEM) >= tgt) return;
  do {
    __builtin_amdgcn_s_sleep(1);
  } while (__hip_atomic_load(p, __ATOMIC_RELAXED, __HIP_MEMORY_SCOPE_SYSTEM) < tgt);
}

__device__ __forceinline__ float tanh_fast(float x) {
  // 1 - 2/(1+e^{2x}); exact at +-inf. ~1e-6 rel err, << fp16 rounding.
  float e = __expf(2.0f * x);
  return 1.0f - 2.0f * __builtin_amdgcn_rcpf(e + 1.0f);
}

__device__ __forceinline__ f32x4 MF(f16x8 a, f16x8 b, f32x4 c) {
  return __builtin_amdgcn_mfma_f32_16x16x32_f16(a, b, c, 0, 0, 0);
}

// ---------------- persistent ESN kernel ----------------

__global__ __launch_bounds__(NTHR, 2) void esn_persist(
    const _Float16* __restrict__ h2hT,   // [RDIM n][RDIM k]  (= h2h[k][n])
    const _Float16* __restrict__ i2hT,   // [RDIM n][IDIM i]
    const _Float16* __restrict__ x16,    // [NB][TT][IDIM]
    _Float16* __restrict__ resbuf,       // [2][NB][RDIM]
    float* __restrict__ pout,            // [16][640]
    unsigned* __restrict__ ctrs,         // [4096]: flag[i]=ctrs[16i], i<128; ctrs[2048]=readout
    const float* __restrict__ out_w,     // [RDIM][10]
    const float* __restrict__ out_b,     // [10]
    float* __restrict__ out)             // [640 + NB*TT*RDIM]
{
  const int bid = blockIdx.x;
  const int rh = bid >> 6;         // row half: batch rows [32rh, 32rh+32)
  const int g = bid & 63;          // column group: cols [32g, 32g+32)
  const int jbase = g * 32;
  const int rbase = rh * 32;
  const int tid = threadIdx.x;
  const int wave = tid >> 6;       // K slice [256*wave, 256*wave+256)
  const int lane = tid & 63;
  const int l15 = lane & 15;
  const int q = lane >> 4;
  const int kslice = wave * 256;

  // B fragments, fragment-major: [wave 8][frag 16][lane 64][8 f16] = 128 KiB
  __shared__ __align__(16) _Float16 blds[8 * 16 * 64 * 8];
  // single accumulation buffer for the 8-way wave reduce (pre-zeroed)
  __shared__ __align__(16) float pl[32][36];

  // ---- prologue: gather B into LDS (one-time) ----
#pragma unroll
  for (int kt = 0; kt < 8; ++kt)
#pragma unroll
    for (int nt = 0; nt < 2; ++nt) {
      int n_abs = jbase + nt * 16 + l15;
      f16x8 bv = *(const f16x8*)(h2hT + (size_t)n_abs * RDIM + kslice + kt * 32 + q * 8);
      *(f16x8*)(blds + (size_t)((wave * 16 + kt * 2 + nt) * 64 + lane) * 8) = bv;
    }
  f16x8 ib[2] = {};
  if (wave < 4) {
#pragma unroll
    for (int nt = 0; nt < 2; ++nt) {
      int n_abs = jbase + nt * 16 + l15;
      ib[nt] = *(const f16x8*)(i2hT + (size_t)n_abs * IDIM + wave * 32 + q * 8);
    }
  }
  for (int i = tid; i < 32 * 36; i += NTHR) ((float*)pl)[i] = 0.f;
  __syncthreads();

  // per-wave poll address: lane k (k = lane&7) watches flag (rh, wave*8 + k)
  const unsigned* fpoll = ctrs + 16 * (rh * 64 + wave * 8 + (lane & 7));

  // reduce mapping: thread owns batch row m = tid>>4, cols [c2, c2+2)
  const int m = tid >> 4;
  const int c2 = (tid & 15) * 2;
  float s[2];
  s[0] = 0.f; s[1] = 0.f;

  const _Float16* bw = blds + (size_t)wave * 16 * 64 * 8;

  for (int t = 0; t < TT; ++t) {
    const _Float16* resp = resbuf + (size_t)(t & 1) * (NB * RDIM);
    const unsigned tgt = (unsigned)t;

    f32x4 acc[2][2] = {};

    // x contribution first: independent of producer flags (waves 0..3 cover IDIM=128)
    if (wave < 4) {
#pragma unroll
      for (int mt = 0; mt < 2; ++mt) {
        f16x8 ax = *(const f16x8*)(x16 + ((size_t)(rbase + mt * 16 + l15) * TT + t) * IDIM + wave * 32 + q * 8);
        acc[mt][0] = MF(ax, ib[0], acc[mt][0]);
        acc[mt][1] = MF(ax, ib[1], acc[mt][1]);
      }
    }

    // hoisted wait: one vector load polls all 8 producer flags of this wave
    {
      unsigned v = __hip_atomic_load(fpoll, __ATOMIC_RELAXED, __HIP_MEMORY_SCOPE_SYSTEM);
      while (!__all(v >= tgt)) {
        __builtin_amdgcn_s_sleep(1);
        v = __hip_atomic_load(fpoll, __ATOMIC_RELAXED, __HIP_MEMORY_SCOPE_SYSTEM);
      }
    }

    // issue ALL 16 A loads; the waitcnt+clobber forces them all in flight
    // (atomic loads can't be rematerialized or sunk past the memory clobber)
    f16x8 A[8][2];
#pragma unroll
    for (int kt = 0; kt < 8; ++kt)
#pragma unroll
      for (int mt = 0; mt < 2; ++mt)
        A[kt][mt] = load_res16(resp + (size_t)(rbase + mt * 16 + l15) * RDIM + kslice + kt * 32 + q * 8);
    asm volatile("s_waitcnt vmcnt(0)" ::: "memory");
    __builtin_amdgcn_sched_barrier(0);

    // MFMA, B streamed from LDS (linear ds_read_b128, conflict-free)
#pragma unroll
    for (int kt = 0; kt < 8; ++kt) {
      f16x8 b0 = *(const f16x8*)(bw + (size_t)((kt * 2 + 0) * 64 + lane) * 8);
      f16x8 b1 = *(const f16x8*)(bw + (size_t)((kt * 2 + 1) * 64 + lane) * 8);
      acc[0][0] = MF(A[kt][0], b0, acc[0][0]);
      acc[1][0] = MF(A[kt][1], b0, acc[1][0]);
      acc[0][1] = MF(A[kt][0], b1, acc[0][1]);
      acc[1][1] = MF(A[kt][1], b1, acc[1][1]);
    }

    // accumulate partials (C/D layout: row = mt*16 + q*4 + r, col = nt*16 + l15)
#pragma unroll
    for (int mt = 0; mt < 2; ++mt)
#pragma unroll
      for (int nt = 0; nt < 2; ++nt)
#pragma unroll
        for (int r = 0; r < 4; ++r)
          atomicAdd(&pl[mt * 16 + q * 4 + r][nt * 16 + l15], acc[mt][nt][r]);
    __syncthreads();
    // Passing this barrier => all 8 waves observed flag[rh*64+g'] >= t for all
    // 64 g' => every row-half-rh WG finished reading res_{t-1} => safe to
    // overwrite that parity region below.

    // read summed partials, re-zero for next step, activation, leak
    float v0 = pl[m][c2];
    float v1 = pl[m][c2 + 1];
    pl[m][c2] = 0.f;
    pl[m][c2 + 1] = 0.f;

    union { _Float16 h[2]; unsigned u; } frag;
    s[0] = 0.5f * s[0] + 0.5f * tanh_fast(v0);
    s[1] = 0.5f * s[1] + 0.5f * tanh_fast(v1);
    frag.h[0] = (_Float16)s[0];
    frag.h[1] = (_Float16)s[1];

    // publish res_{t+1} (write-through system stores)
    _Float16* resw = resbuf + (size_t)((t + 1) & 1) * (NB * RDIM);
    __hip_atomic_store((unsigned*)(resw + (size_t)(rbase + m) * RDIM + jbase + c2),
                       frag.u, __ATOMIC_RELAXED, __HIP_MEMORY_SCOPE_SYSTEM);
    __syncthreads();  // each wave drains its vmcnt before barrier -> all res stores visible
    if (tid == 0)
      __hip_atomic_store(&ctrs[16 * bid], (unsigned)(t + 1), __ATOMIC_RELAXED,
                         __HIP_MEMORY_SCOPE_SYSTEM);

    // hiddens AFTER flag publish: off the critical path
    f32x2 hv;
    hv[0] = s[0]; hv[1] = s[1];
    float* hid = out + 640 + ((size_t)(rbase + m) * TT + t) * RDIM + jbase + c2;
    __builtin_nontemporal_store(hv, (f32x2*)hid);
  }

  // ---------------- final readout: out = res_256 @ out_w + out_b ----------------
  if (bid < 16) {
    // this WG's K-slice [128*bid, 128*bid+128) was produced by col groups
    // 4bid..4bid+3 in BOTH row halves.
    if (tid == 0) {
      for (int rh2 = 0; rh2 < 2; ++rh2)
        for (int j = 0; j < 4; ++j)
          waitflag(ctrs + 16 * (rh2 * 64 + 4 * bid + j), (unsigned)TT);
    }
    __syncthreads();
    const _Float16* rlast = resbuf;  // parity (256 & 1) = 0
    for (int o = tid; o < 640; o += NTHR) {
      int b = o / 10, oo = o - 10 * b;
      float a = 0.f;
      const unsigned* rp = (const unsigned*)(rlast + (size_t)b * RDIM + bid * 128);
      for (int r2 = 0; r2 < 64; ++r2) {
        union { unsigned u; _Float16 h[2]; } cv;
        cv.u = __hip_atomic_load(rp + r2, __ATOMIC_RELAXED, __HIP_MEMORY_SCOPE_SYSTEM);
        a += (float)cv.h[0] * out_w[(size_t)(bid * 128 + 2 * r2) * 10 + oo];
        a += (float)cv.h[1] * out_w[(size_t)(bid * 128 + 2 * r2 + 1) * 10 + oo];
      }
      __hip_atomic_store(&pout[bid * 640 + o], a, __ATOMIC_RELAXED, __HIP_MEMORY_SCOPE_SYSTEM);
    }
    __syncthreads();
    if (tid == 0)
      __hip_atomic_fetch_add(&ctrs[2048], 1u, __ATOMIC_RELAXED, __HIP_MEMORY_SCOPE_SYSTEM);
    if (bid == 0) {
      if (tid == 0) {
        while (__hip_atomic_load(&ctrs[2048], __ATOMIC_RELAXED, __HIP_MEMORY_SCOPE_SYSTEM) < 16u)
          __builtin_amdgcn_s_sleep(1);
      }
      __syncthreads();
      for (int o = tid; o < 640; o += NTHR) {
        float a = out_b[o % 10];
        for (int kk = 0; kk < 16; ++kk)
          a += __hip_atomic_load(&pout[kk * 640 + o], __ATOMIC_RELAXED, __HIP_MEMORY_SCOPE_SYSTEM);
        out[o] = a;
      }
    }
  }
}

// ---------------- host launcher ----------------

extern "C" void kernel_launch(void* const* d_in, const int* in_sizes, int n_in,
                              void* d_out, int out_size, void* d_ws, size_t ws_size,
                              hipStream_t stream) {
  const float* x     = (const float*)d_in[0];  // (64,256,128)
  const float* i2h_w = (const float*)d_in[1];  // (128,2048)
  const float* h2h   = (const float*)d_in[2];  // (2048,2048)
  const float* out_w = (const float*)d_in[3];  // (2048,10)
  const float* out_b = (const float*)d_in[4];  // (10,)
  float* out = (float*)d_out;

  unsigned char* ws = (unsigned char*)d_ws;
  _Float16* h2hT   = (_Float16*)(ws + 0);             // 8,388,608
  _Float16* i2hT   = (_Float16*)(ws + 8388608);       //   524,288
  _Float16* x16    = (_Float16*)(ws + 8912896);       // 4,194,304
  _Float16* resbuf = (_Float16*)(ws + 13107200);      //   524,288
  float*    pout   = (float*)   (ws + 13631488);      //    40,960
  unsigned* ctrs   = (unsigned*)(ws + 13672448);      //    16,384
  // total ~13.7 MB

  transpose_f32_to_f16<<<dim3(32, 32), dim3(256), 0, stream>>>(h2h, h2hT, 2048, 2048);
  transpose_f32_to_f16<<<dim3(32, 2), dim3(256), 0, stream>>>(i2h_w, i2hT, 128, 2048);
  convert_f32_f16<<<dim3(512), dim3(256), 0, stream>>>(x, x16, NB * TT * IDIM);
  init_zero<<<dim3(256), dim3(256), 0, stream>>>((unsigned*)resbuf, ctrs);
  esn_persist<<<dim3(NWG), dim3(NTHR), 0, stream>>>(h2hT, i2hT, x16, resbuf, pout,
                                                    ctrs, out_w, out_b, out);
}

// Round 4
// 2308.314 us; speedup vs baseline: 1.6237x; 1.6237x over previous
//
#include <hip/hip_runtime.h>

// ESN leaky reservoir: res_{t+1} = 0.5*res_t + 0.5*tanh(x_t@i2h + res_t@h2h)
// Round 8: R6 structure (best: 2183us), ONE variable changed:
//   SYSTEM-scope atomics -> AGENT (device) scope for all res/flag/pout traffic.
// Rationale (from R6/R7 counters): WRITE_SIZE showed res publishes reaching
// HBM every step (system scope = sc0 sc1, write-through PAST L3). The step
// critical path is publish-drain + flag-detect round trips; system scope pins
// those to HBM latency. Agent scope (sc1) is coherent at the die-level L3,
// which is shared by all 8 XCDs -> cross-XCD exchange stays correct, round
// trips drop to L3 latency. R7's lesson also applied: no hard vmcnt(0) drain /
// sched_barrier on the load path (it serialized stalls; compiler scheduling of
// the R6 loop was already better).

typedef _Float16 f16x8 __attribute__((ext_vector_type(8)));
typedef float f32x4 __attribute__((ext_vector_type(4)));
typedef float f32x2 __attribute__((ext_vector_type(2)));

#define NB 64      // batch
#define RDIM 2048  // reservoir
#define TT 256     // timesteps
#define IDIM 128   // input dim
#define NWG 128    // 2 row-halves x 64 col-groups
#define NTHR 512   // threads per WG (8 waves)

#define SCOPE __HIP_MEMORY_SCOPE_AGENT  // device scope: coherent at L3 (cross-XCD)

// ---------------- setup kernels ----------------

__global__ __launch_bounds__(256) void transpose_f32_to_f16(
    const float* __restrict__ in, _Float16* __restrict__ out, int rows, int cols) {
  __shared__ float tile[64][65];
  const int tx = threadIdx.x & 63;
  const int ty = threadIdx.x >> 6;
  const int rbase = blockIdx.y * 64;
  const int cbase = blockIdx.x * 64;
  for (int rr = ty; rr < 64; rr += 4)
    tile[rr][tx] = in[(size_t)(rbase + rr) * cols + cbase + tx];
  __syncthreads();
  for (int rr = ty; rr < 64; rr += 4)
    out[(size_t)(cbase + rr) * rows + rbase + tx] = (_Float16)tile[tx][rr];
}

__global__ __launch_bounds__(256) void convert_f32_f16(
    const float* __restrict__ in, _Float16* __restrict__ out, int n) {
  int i = blockIdx.x * 256 + threadIdx.x;
  int stride = gridDim.x * 256;
  for (; i < n; i += stride) out[i] = (_Float16)in[i];
}

__global__ __launch_bounds__(256) void init_zero(
    unsigned* __restrict__ res_words, unsigned* __restrict__ ctr_words) {
  int i = blockIdx.x * 256 + threadIdx.x;
  if (i < NB * RDIM / 2) res_words[i] = 0;  // res parity-0 buffer (fp16) = 0
  if (i < 4096) ctr_words[i] = 0;           // flags (128 x 16-word spaced) + readout ctr
}

// ---------------- coherent access helpers (agent scope, no fences) ----------------

__device__ __forceinline__ f16x8 load_res16(const _Float16* p) {
  union { unsigned long long u[2]; f16x8 v; } r;
  const unsigned long long* q = (const unsigned long long*)p;
  r.u[0] = __hip_atomic_load(q, __ATOMIC_RELAXED, SCOPE);
  r.u[1] = __hip_atomic_load(q + 1, __ATOMIC_RELAXED, SCOPE);
  return r.v;
}

// flag[i] lives at ctrs[16*i] (64B spacing). Value = last published step index.
__device__ __forceinline__ void waitflag(const unsigned* p, unsigned tgt) {
  if (__hip_atomic_load(p, __ATOMIC_RELAXED, SCOPE) >= tgt) return;
  do {
    __builtin_amdgcn_s_sleep(1);
  } while (__hip_atomic_load(p, __ATOMIC_RELAXED, SCOPE) < tgt);
}

__device__ __forceinline__ float tanh_fast(float x) {
  // 1 - 2/(1+e^{2x}); exact at +-inf. ~1e-6 rel err, << fp16 rounding.
  float e = __expf(2.0f * x);
  return 1.0f - 2.0f * __builtin_amdgcn_rcpf(e + 1.0f);
}

__device__ __forceinline__ f32x4 MF(f16x8 a, f16x8 b, f32x4 c) {
  return __builtin_amdgcn_mfma_f32_16x16x32_f16(a, b, c, 0, 0, 0);
}

// ---------------- persistent ESN kernel ----------------

__global__ __launch_bounds__(NTHR, 2) void esn_persist(
    const _Float16* __restrict__ h2hT,   // [RDIM n][RDIM k]  (= h2h[k][n])
    const _Float16* __restrict__ i2hT,   // [RDIM n][IDIM i]
    const _Float16* __restrict__ x16,    // [NB][TT][IDIM]
    _Float16* __restrict__ resbuf,       // [2][NB][RDIM]
    float* __restrict__ pout,            // [16][640]
    unsigned* __restrict__ ctrs,         // [4096]: flag[i]=ctrs[16i], i<128; ctrs[2048]=readout
    const float* __restrict__ out_w,     // [RDIM][10]
    const float* __restrict__ out_b,     // [10]
    float* __restrict__ out)             // [640 + NB*TT*RDIM]
{
  const int bid = blockIdx.x;
  const int rh = bid >> 6;         // row half: batch rows [32rh, 32rh+32)
  const int g = bid & 63;          // column group: cols [32g, 32g+32)
  const int jbase = g * 32;
  const int rbase = rh * 32;
  const int tid = threadIdx.x;
  const int wave = tid >> 6;       // K slice [256*wave, 256*wave+256)
  const int lane = tid & 63;
  const int l15 = lane & 15;
  const int q = lane >> 4;
  const int kslice = wave * 256;

  // Stationary B fragments: lane holds B[kslice + kt*32 + q*8 + jj][n_abs]
  f16x8 bfr[8][2];
#pragma unroll
  for (int kt = 0; kt < 8; ++kt)
#pragma unroll
    for (int nt = 0; nt < 2; ++nt) {
      int n_abs = jbase + nt * 16 + l15;
      bfr[kt][nt] = *(const f16x8*)(h2hT + (size_t)n_abs * RDIM + kslice + kt * 32 + q * 8);
    }
  f16x8 ib[2] = {};
  if (wave < 4) {
#pragma unroll
    for (int nt = 0; nt < 2; ++nt) {
      int n_abs = jbase + nt * 16 + l15;
      ib[nt] = *(const f16x8*)(i2hT + (size_t)n_abs * IDIM + wave * 32 + q * 8);
    }
  }

  // per-wave poll address: lane k (k = lane&7) watches flag (rh, wave*8 + k)
  const unsigned* fpoll = ctrs + 16 * (rh * 64 + wave * 8 + (lane & 7));

  // LDS partial buffer: [wave][m 32][col 32] padded to 36
  __shared__ __align__(16) float pl[8][32][36];

  // reduce mapping: thread owns row m = tid>>4, cols [c2, c2+2)
  const int m = tid >> 4;
  const int c2 = (tid & 15) * 2;
  float s[2];
  s[0] = 0.f; s[1] = 0.f;

  for (int t = 0; t < TT; ++t) {
    const _Float16* resp = resbuf + (size_t)(t & 1) * (NB * RDIM);
    const unsigned tgt = (unsigned)t;

    f32x4 acc[2][2] = {};

    // x contribution first: independent of producer flags (waves 0..3 cover IDIM=128)
    if (wave < 4) {
#pragma unroll
      for (int mt = 0; mt < 2; ++mt) {
        f16x8 ax = *(const f16x8*)(x16 + ((size_t)(rbase + mt * 16 + l15) * TT + t) * IDIM + wave * 32 + q * 8);
        acc[mt][0] = MF(ax, ib[0], acc[mt][0]);
        acc[mt][1] = MF(ax, ib[1], acc[mt][1]);
      }
    }

    // hoisted wait: one vector load polls all 8 producer flags of this wave
    {
      unsigned v = __hip_atomic_load(fpoll, __ATOMIC_RELAXED, SCOPE);
      while (!__all(v >= tgt)) {
        __builtin_amdgcn_s_sleep(1);
        v = __hip_atomic_load(fpoll, __ATOMIC_RELAXED, SCOPE);
      }
    }

    // issue ALL chunk loads back-to-back, then MFMA (compiler-scheduled; R7
    // showed a hard vmcnt(0)+sched_barrier here only adds convoy stalls)
    f16x8 A[8][2];
#pragma unroll
    for (int kt = 0; kt < 8; ++kt)
#pragma unroll
      for (int mt = 0; mt < 2; ++mt)
        A[kt][mt] = load_res16(resp + (size_t)(rbase + mt * 16 + l15) * RDIM + kslice + kt * 32 + q * 8);
#pragma unroll
    for (int kt = 0; kt < 8; ++kt)
#pragma unroll
      for (int mt = 0; mt < 2; ++mt) {
        acc[mt][0] = MF(A[kt][mt], bfr[kt][0], acc[mt][0]);
        acc[mt][1] = MF(A[kt][mt], bfr[kt][1], acc[mt][1]);
      }

    // stash partials in LDS (C/D layout: m = mt*16 + q*4 + r, n = nt*16 + l15)
#pragma unroll
    for (int mt = 0; mt < 2; ++mt)
#pragma unroll
      for (int nt = 0; nt < 2; ++nt)
#pragma unroll
        for (int r = 0; r < 4; ++r)
          pl[wave][mt * 16 + q * 4 + r][nt * 16 + l15] = acc[mt][nt][r];
    __syncthreads();
    // Passing this barrier => this WG observed flag[rh*64+g'] >= t for ALL 64 g'
    // => every row-half-rh WG finished reading res_{t-1} rows rh => safe to
    // overwrite that region below.

    // 8-way reduce, activation, leak
    f32x2 v = *(const f32x2*)&pl[0][m][c2];
#pragma unroll
    for (int w = 1; w < 8; ++w) v += *(const f32x2*)&pl[w][m][c2];

    union { _Float16 h[2]; unsigned u; } frag;
#pragma unroll
    for (int r = 0; r < 2; ++r) {
      s[r] = 0.5f * s[r] + 0.5f * tanh_fast(v[r]);
      frag.h[r] = (_Float16)s[r];
    }

    // publish res_{t+1} (write-through-to-L3 device-scope stores)
    _Float16* resw = resbuf + (size_t)((t + 1) & 1) * (NB * RDIM);
    __hip_atomic_store((unsigned*)(resw + (size_t)(rbase + m) * RDIM + jbase + c2),
                       frag.u, __ATOMIC_RELAXED, SCOPE);
    __syncthreads();  // drains vmcnt per wave -> all res stores visible at L3
    if (tid == 0)
      __hip_atomic_store(&ctrs[16 * bid], (unsigned)(t + 1), __ATOMIC_RELAXED, SCOPE);

    // hiddens AFTER flag publish: off the critical path
    f32x2 hv;
    hv[0] = s[0]; hv[1] = s[1];
    float* hid = out + 640 + ((size_t)(rbase + m) * TT + t) * RDIM + jbase + c2;
    __builtin_nontemporal_store(hv, (f32x2*)hid);
  }

  // ---------------- final readout: out = res_256 @ out_w + out_b ----------------
  if (bid < 16) {
    // this WG's K-slice [128*bid, 128*bid+128) was produced by col groups
    // 4bid..4bid+3 in BOTH row halves.
    if (tid == 0) {
      for (int rh2 = 0; rh2 < 2; ++rh2)
        for (int j = 0; j < 4; ++j)
          waitflag(ctrs + 16 * (rh2 * 64 + 4 * bid + j), (unsigned)TT);
    }
    __syncthreads();
    const _Float16* rlast = resbuf;  // parity (256 & 1) = 0
    for (int o = tid; o < 640; o += NTHR) {
      int b = o / 10, oo = o - 10 * b;
      float a = 0.f;
      const unsigned* rp = (const unsigned*)(rlast + (size_t)b * RDIM + bid * 128);
      for (int r2 = 0; r2 < 64; ++r2) {
        union { unsigned u; _Float16 h[2]; } cv;
        cv.u = __hip_atomic_load(rp + r2, __ATOMIC_RELAXED, SCOPE);
        a += (float)cv.h[0] * out_w[(size_t)(bid * 128 + 2 * r2) * 10 + oo];
        a += (float)cv.h[1] * out_w[(size_t)(bid * 128 + 2 * r2 + 1) * 10 + oo];
      }
      __hip_atomic_store(&pout[bid * 640 + o], a, __ATOMIC_RELAXED, SCOPE);
    }
    __syncthreads();
    if (tid == 0)
      __hip_atomic_fetch_add(&ctrs[2048], 1u, __ATOMIC_RELAXED, SCOPE);
    if (bid == 0) {
      if (tid == 0) {
        while (__hip_atomic_load(&ctrs[2048], __ATOMIC_RELAXED, SCOPE) < 16u)
          __builtin_amdgcn_s_sleep(1);
      }
      __syncthreads();
      for (int o = tid; o < 640; o += NTHR) {
        float a = out_b[o % 10];
        for (int kk = 0; kk < 16; ++kk)
          a += __hip_atomic_load(&pout[kk * 640 + o], __ATOMIC_RELAXED, SCOPE);
        out[o] = a;
      }
    }
  }
}

// ---------------- host launcher ----------------

extern "C" void kernel_launch(void* const* d_in, const int* in_sizes, int n_in,
                              void* d_out, int out_size, void* d_ws, size_t ws_size,
                              hipStream_t stream) {
  const float* x     = (const float*)d_in[0];  // (64,256,128)
  const float* i2h_w = (const float*)d_in[1];  // (128,2048)
  const float* h2h   = (const float*)d_in[2];  // (2048,2048)
  const float* out_w = (const float*)d_in[3];  // (2048,10)
  const float* out_b = (const float*)d_in[4];  // (10,)
  float* out = (float*)d_out;

  unsigned char* ws = (unsigned char*)d_ws;
  _Float16* h2hT   = (_Float16*)(ws + 0);             // 8,388,608
  _Float16* i2hT   = (_Float16*)(ws + 8388608);       //   524,288
  _Float16* x16    = (_Float16*)(ws + 8912896);       // 4,194,304
  _Float16* resbuf = (_Float16*)(ws + 13107200);      //   524,288
  float*    pout   = (float*)   (ws + 13631488);      //    40,960
  unsigned* ctrs   = (unsigned*)(ws + 13672448);      //    16,384
  // total ~13.7 MB

  transpose_f32_to_f16<<<dim3(32, 32), dim3(256), 0, stream>>>(h2h, h2hT, 2048, 2048);
  transpose_f32_to_f16<<<dim3(32, 2), dim3(256), 0, stream>>>(i2h_w, i2hT, 128, 2048);
  convert_f32_f16<<<dim3(512), dim3(256), 0, stream>>>(x, x16, NB * TT * IDIM);
  init_zero<<<dim3(256), dim3(256), 0, stream>>>((unsigned*)resbuf, ctrs);
  esn_persist<<<dim3(NWG), dim3(NTHR), 0, stream>>>(h2hT, i2hT, x16, resbuf, pout,
                                                    ctrs, out_w, out_b, out);
}